// Round 2
// baseline (3560.616 us; speedup 1.0000x reference)
//
#include <hip/hip_runtime.h>

#define NHID   1024
#define BATCH  128
#define LSTEPS 1000
#define DTC    0.042f
#define THETA  1.0f
#define TAUM   20.0f
#define NT     512           // threads per block; each owns units t and t+512
#define ROWB   4096          // bytes per weight-matrix row (1024 * 4)

// One block per batch element. Spike matmuls (binary left operand) become
// sparse row accumulations over LDS index lists, built by parallel ballot
// decode (popcount-prefix, no serial ffs). Accumulation order is strictly
// ascending j -> numerically identical to the previous passing kernel.
__global__ __launch_bounds__(NT) void coesn_sim(
    const float* __restrict__ x,        // (B, L, 1)
    const float* __restrict__ x2h,      // (1, H)
    const float* __restrict__ h2h,      // (H, H)
    const float* __restrict__ bias,     // (H)
    const float* __restrict__ lif2hrf,  // (H, H)
    const float* __restrict__ gamma_,   // (H)
    const float* __restrict__ eps_,     // (H)
    float* __restrict__ out,            // (B, 3H) features
    unsigned int* __restrict__ ws)      // (B, 2) spike counts
{
    const int b    = blockIdx.x;
    const int tid  = threadIdx.x;
    const int wv   = tid >> 6;          // 0..7
    const int lane = tid & 63;
    const int h1   = tid;
    const int h2   = tid + NT;

    __shared__ unsigned int list_s[16][64];  // HRF spike row byte-offsets (prev step)
    __shared__ unsigned int list_l[16][64];  // LIF spike row byte-offsets (this step)
    __shared__ int cnt_s[16];
    __shared__ int cnt_l[16];
    __shared__ unsigned int red[8];

    if (tid < 16) cnt_s[tid] = 0;

    float hy1 = 0.f, hz1 = 0.f, v1 = 0.f, rp1 = 0.f;
    float hy2 = 0.f, hz2 = 0.f, v2 = 0.f, rp2 = 0.f;
    float hysum1 = 0.f, hysq1 = 0.f, hysum2 = 0.f, hysq2 = 0.f;
    unsigned int chrf = 0, clif = 0;

    const float g1 = gamma_[h1], g2 = gamma_[h2];
    const float e1 = eps_[h1],  e2 = eps_[h2];
    const float bi1 = bias[h1], bi2 = bias[h2];
    const float win1 = x2h[h1], win2 = x2h[h2];
    const float ref_decay = expf((float)(-0.042 / 0.25));
    const float* xb = x + (size_t)b * LSTEPS;

    const char* hb1 = (const char*)h2h + 4 * (size_t)h1;
    const char* hb2 = (const char*)h2h + 4 * (size_t)h2;
    const char* lb1 = (const char*)lif2hrf + 4 * (size_t)h1;
    const char* lb2 = (const char*)lif2hrf + 4 * (size_t)h2;

    const unsigned long long below = (lane == 63) ? ~0ULL >> 1
                                    : ((1ULL << lane) - 1ULL);

    __syncthreads();

    for (int t = 0; t < LSTEPS; ++t) {
        // ---- phase A: cur = x*x2h + s@h2h + bias (sparse row-accumulate) ----
        const float xv = xb[t];
        float cur1 = xv * win1 + bi1;
        float cur2 = xv * win2 + bi2;
        for (int w = 0; w < 16; ++w) {
            const int n = cnt_s[w];
            const unsigned int* lp = list_s[w];
            int k = 0;
            for (; k + 3 < n; k += 4) {
                const unsigned o0 = lp[k], o1 = lp[k+1], o2 = lp[k+2], o3 = lp[k+3];
                const float a0 = *(const float*)(hb1 + o0);
                const float a1 = *(const float*)(hb1 + o1);
                const float a2 = *(const float*)(hb1 + o2);
                const float a3 = *(const float*)(hb1 + o3);
                const float c0 = *(const float*)(hb2 + o0);
                const float c1 = *(const float*)(hb2 + o1);
                const float c2 = *(const float*)(hb2 + o2);
                const float c3 = *(const float*)(hb2 + o3);
                cur1 += a0; cur1 += a1; cur1 += a2; cur1 += a3;
                cur2 += c0; cur2 += c1; cur2 += c2; cur2 += c3;
            }
            for (; k < n; ++k) {
                const unsigned o = lp[k];
                cur1 += *(const float*)(hb1 + o);
                cur2 += *(const float*)(hb2 + o);
            }
        }

        // ---- phase B: LIF update + spike + ballot-decode into list_l ----
        v1 = v1 + DTC * (-v1 / TAUM + cur1);
        v2 = v2 + DTC * (-v2 / TAUM + cur2);
        const float ls1 = (v1 > THETA) ? 1.f : 0.f;
        const float ls2 = (v2 > THETA) ? 1.f : 0.f;
        v1 -= ls1 * THETA;
        v2 -= ls2 * THETA;
        clif += (unsigned)ls1 + (unsigned)ls2;
        {
            const unsigned long long bA = __ballot(ls1 > 0.5f);
            const unsigned long long bB = __ballot(ls2 > 0.5f);
            if (ls1 > 0.5f) list_l[wv][__popcll(bA & below)]     = (unsigned)(h1 * ROWB);
            if (ls2 > 0.5f) list_l[8 + wv][__popcll(bB & below)] = (unsigned)(h2 * ROWB);
            if (lane == 0) { cnt_l[wv] = __popcll(bA); cnt_l[8 + wv] = __popcll(bB); }
        }
        __syncthreads();

        // ---- phase C: drive = lif_s @ lif2hrf ----
        float dr1 = 0.f, dr2 = 0.f;
        for (int w = 0; w < 16; ++w) {
            const int n = cnt_l[w];
            const unsigned int* lp = list_l[w];
            int k = 0;
            for (; k + 3 < n; k += 4) {
                const unsigned o0 = lp[k], o1 = lp[k+1], o2 = lp[k+2], o3 = lp[k+3];
                const float a0 = *(const float*)(lb1 + o0);
                const float a1 = *(const float*)(lb1 + o1);
                const float a2 = *(const float*)(lb1 + o2);
                const float a3 = *(const float*)(lb1 + o3);
                const float c0 = *(const float*)(lb2 + o0);
                const float c1 = *(const float*)(lb2 + o1);
                const float c2 = *(const float*)(lb2 + o2);
                const float c3 = *(const float*)(lb2 + o3);
                dr1 += a0; dr1 += a1; dr1 += a2; dr1 += a3;
                dr2 += c0; dr2 += c1; dr2 += c2; dr2 += c3;
            }
            for (; k < n; ++k) {
                const unsigned o = lp[k];
                dr1 += *(const float*)(lb1 + o);
                dr2 += *(const float*)(lb2 + o);
            }
        }

        // ---- phase D: HRF update + spike + stats + ballot-decode into list_s ----
        hz1 = hz1 + DTC * (dr1 - g1 * hy1 - e1 * hz1);
        hz2 = hz2 + DTC * (dr2 - g2 * hy2 - e2 * hz2);
        hy1 = hy1 + DTC * hz1;
        hy2 = hy2 + DTC * hz2;
        const float s1 = ((hy1 - THETA - rp1) > 0.f) ? 1.f : 0.f;
        const float s2 = ((hy2 - THETA - rp2) > 0.f) ? 1.f : 0.f;
        rp1 = rp1 * ref_decay + s1;
        rp2 = rp2 * ref_decay + s2;
        hysum1 += hy1; hysq1 += hy1 * hy1;
        hysum2 += hy2; hysq2 += hy2 * hy2;
        chrf += (unsigned)s1 + (unsigned)s2;
        {
            const unsigned long long bA = __ballot(s1 > 0.5f);
            const unsigned long long bB = __ballot(s2 > 0.5f);
            if (s1 > 0.5f) list_s[wv][__popcll(bA & below)]     = (unsigned)(h1 * ROWB);
            if (s2 > 0.5f) list_s[8 + wv][__popcll(bB & below)] = (unsigned)(h2 * ROWB);
            if (lane == 0) { cnt_s[wv] = __popcll(bA); cnt_s[8 + wv] = __popcll(bB); }
        }
        __syncthreads();
    }

    // ---- epilogue: features for both units ----
    const float Lf = (float)LSTEPS;
    float* ob = out + (size_t)b * (3 * NHID);
    {
        const float mean = hysum1 / Lf;
        const float rms  = sqrtf(hysq1 / Lf + 1e-8f);
        float var = hysq1 / Lf - mean * mean;
        var = fmaxf(var, 1e-8f);
        ob[h1]            = rms;
        ob[NHID + h1]     = sqrtf(var);
        ob[2 * NHID + h1] = hy1;
    }
    {
        const float mean = hysum2 / Lf;
        const float rms  = sqrtf(hysq2 / Lf + 1e-8f);
        float var = hysq2 / Lf - mean * mean;
        var = fmaxf(var, 1e-8f);
        ob[h2]            = rms;
        ob[NHID + h2]     = sqrtf(var);
        ob[2 * NHID + h2] = hy2;
    }

    // ---- spike-count reduction ----
    unsigned int c = chrf;
    for (int off = 32; off > 0; off >>= 1) c += __shfl_down(c, off, 64);
    if (lane == 0) red[wv] = c;
    __syncthreads();
    if (tid == 0) {
        unsigned int tot = 0;
        for (int i = 0; i < 8; ++i) tot += red[i];
        ws[b * 2] = tot;
    }
    __syncthreads();
    c = clif;
    for (int off = 32; off > 0; off >>= 1) c += __shfl_down(c, off, 64);
    if (lane == 0) red[wv] = c;
    __syncthreads();
    if (tid == 0) {
        unsigned int tot = 0;
        for (int i = 0; i < 8; ++i) tot += red[i];
        ws[b * 2 + 1] = tot;
    }
}

__global__ void coesn_final(const unsigned int* __restrict__ ws,
                            float* __restrict__ out)
{
    if (threadIdx.x == 0 && blockIdx.x == 0) {
        unsigned long long hrf = 0, lif = 0;
        for (int b = 0; b < BATCH; ++b) {
            hrf += ws[b * 2];
            lif += ws[b * 2 + 1];
        }
        const float denom = (float)BATCH * (float)LSTEPS * (float)NHID;
        const float r_hrf = (float)hrf / denom;
        const float r_lif = (float)lif / denom;
        float* s = out + (size_t)BATCH * 3 * NHID;
        s[0] = r_hrf;
        s[1] = r_hrf;
        s[2] = r_lif;
    }
}

extern "C" void kernel_launch(void* const* d_in, const int* in_sizes, int n_in,
                              void* d_out, int out_size, void* d_ws, size_t ws_size,
                              hipStream_t stream) {
    const float* x       = (const float*)d_in[0];
    const float* x2h     = (const float*)d_in[1];
    const float* h2h     = (const float*)d_in[2];
    const float* bias    = (const float*)d_in[3];
    const float* lif2hrf = (const float*)d_in[4];
    const float* gamma_  = (const float*)d_in[5];
    const float* eps_    = (const float*)d_in[6];
    float* out = (float*)d_out;
    unsigned int* wsp = (unsigned int*)d_ws;

    coesn_sim<<<BATCH, NT, 0, stream>>>(x, x2h, h2h, bias, lif2hrf, gamma_, eps_, out, wsp);
    coesn_final<<<1, 64, 0, stream>>>(wsp, out);
}

// Round 3
// 1584.207 us; speedup vs baseline: 2.2476x; 2.2476x over previous
//
#include <hip/hip_runtime.h>

#define NHID    1024
#define BATCH   128
#define LSTEPS  1000
#define DTC     0.042f
#define THETA   1.0f
#define TAUM    20.0f
#define LISTCAP 1032          // 1024 + pad for 8-wide predicated tail

// One block per batch element; thread h owns hidden unit h (16 waves/CU).
// Binary-spike matmuls = sparse row gathers over ONE combined LDS offset list
// per phase, built by ballot + cross-wave popcount prefix. List order is
// ascending j -> f32 accumulation order identical to the R1 passing kernel.
__global__ __launch_bounds__(1024) void coesn_sim(
    const float* __restrict__ x,        // (B, L, 1)
    const float* __restrict__ x2h,      // (1, H)
    const float* __restrict__ h2h,      // (H, H)
    const float* __restrict__ bias,     // (H)
    const float* __restrict__ lif2hrf,  // (H, H)
    const float* __restrict__ gamma_,   // (H)
    const float* __restrict__ eps_,     // (H)
    float* __restrict__ out,            // (B, 3H) features
    unsigned int* __restrict__ ws)      // (B, 2) spike counts
{
    const int b    = blockIdx.x;
    const int h    = threadIdx.x;
    const int wv   = h >> 6;
    const int lane = h & 63;

    __shared__ unsigned int Ls[LISTCAP];  // HRF spike row byte-offsets (for phase A)
    __shared__ unsigned int Ll[LISTCAP];  // LIF spike row byte-offsets (for phase C)
    __shared__ int Cs[16], Cl[16];
    __shared__ unsigned int red[16];

    Ls[h] = 0; Ll[h] = 0;
    if (h < LISTCAP - 1024) { Ls[1024 + h] = 0; Ll[1024 + h] = 0; }
    if (h < 16) { Cs[h] = 0; Cl[h] = 0; }

    float hy = 0.f, hz = 0.f, v = 0.f, rp = 0.f;
    float hysum = 0.f, hysq = 0.f;
    unsigned int chrf = 0, clif = 0;

    const float g    = gamma_[h];
    const float e    = eps_[h];
    const float bi   = bias[h];
    const float win  = x2h[h];
    const float ref_decay = expf((float)(-0.042 / 0.25));
    const float* xb  = x + (size_t)b * LSTEPS;

    const char* hb = (const char*)h2h     + 4 * (size_t)h;
    const char* lb = (const char*)lif2hrf + 4 * (size_t)h;

    const unsigned long long below = (1ULL << lane) - 1ULL;  // lane=63 ok

    int ns = 0;   // HRF list length (phase A bound); 0 at t=0

    __syncthreads();

    for (int t = 0; t < LSTEPS; ++t) {
        // ---- phase A: cur = x*x2h + bias + sum of spiking h2h rows ----
        const float xv = xb[t];
        float cur = xv * win + bi;
        for (int k = 0; k < ns; k += 8) {
            const unsigned o0 = Ls[k+0], o1 = Ls[k+1], o2 = Ls[k+2], o3 = Ls[k+3];
            const unsigned o4 = Ls[k+4], o5 = Ls[k+5], o6 = Ls[k+6], o7 = Ls[k+7];
            const float a0 = *(const float*)(hb + o0);
            const float a1 = *(const float*)(hb + o1);
            const float a2 = *(const float*)(hb + o2);
            const float a3 = *(const float*)(hb + o3);
            const float a4 = *(const float*)(hb + o4);
            const float a5 = *(const float*)(hb + o5);
            const float a6 = *(const float*)(hb + o6);
            const float a7 = *(const float*)(hb + o7);
            cur += a0;
            cur += (k+1 < ns) ? a1 : 0.0f;
            cur += (k+2 < ns) ? a2 : 0.0f;
            cur += (k+3 < ns) ? a3 : 0.0f;
            cur += (k+4 < ns) ? a4 : 0.0f;
            cur += (k+5 < ns) ? a5 : 0.0f;
            cur += (k+6 < ns) ? a6 : 0.0f;
            cur += (k+7 < ns) ? a7 : 0.0f;
        }

        // ---- phase B: LIF update + spike + list build ----
        v = v + DTC * (-v / TAUM + cur);
        const float lsp = (v > THETA) ? 1.f : 0.f;
        v -= lsp * THETA;
        clif += (unsigned)lsp;
        const unsigned long long balL = __ballot(lsp > 0.5f);
        if (lane == 0) Cl[wv] = __popcll(balL);
        __syncthreads();
        int pre = 0, nl = 0;
        for (int i = 0; i < 16; ++i) { const int c = Cl[i]; pre += (i < wv) ? c : 0; nl += c; }
        if (lsp > 0.5f) Ll[pre + __popcll(balL & below)] = (unsigned)(h * 4096);
        __syncthreads();

        // ---- phase C: drive = sum of spiking lif2hrf rows ----
        float dr = 0.f;
        for (int k = 0; k < nl; k += 8) {
            const unsigned o0 = Ll[k+0], o1 = Ll[k+1], o2 = Ll[k+2], o3 = Ll[k+3];
            const unsigned o4 = Ll[k+4], o5 = Ll[k+5], o6 = Ll[k+6], o7 = Ll[k+7];
            const float a0 = *(const float*)(lb + o0);
            const float a1 = *(const float*)(lb + o1);
            const float a2 = *(const float*)(lb + o2);
            const float a3 = *(const float*)(lb + o3);
            const float a4 = *(const float*)(lb + o4);
            const float a5 = *(const float*)(lb + o5);
            const float a6 = *(const float*)(lb + o6);
            const float a7 = *(const float*)(lb + o7);
            dr += a0;
            dr += (k+1 < nl) ? a1 : 0.0f;
            dr += (k+2 < nl) ? a2 : 0.0f;
            dr += (k+3 < nl) ? a3 : 0.0f;
            dr += (k+4 < nl) ? a4 : 0.0f;
            dr += (k+5 < nl) ? a5 : 0.0f;
            dr += (k+6 < nl) ? a6 : 0.0f;
            dr += (k+7 < nl) ? a7 : 0.0f;
        }

        // ---- phase D: HRF update + spike + stats + list build ----
        hz = hz + DTC * (dr - g * hy - e * hz);
        hy = hy + DTC * hz;
        const float sn = ((hy - THETA - rp) > 0.f) ? 1.f : 0.f;
        rp = rp * ref_decay + sn;
        hysum += hy;
        hysq  += hy * hy;
        chrf += (unsigned)sn;
        const unsigned long long balS = __ballot(sn > 0.5f);
        if (lane == 0) Cs[wv] = __popcll(balS);
        __syncthreads();
        pre = 0; ns = 0;
        for (int i = 0; i < 16; ++i) { const int c = Cs[i]; pre += (i < wv) ? c : 0; ns += c; }
        if (sn > 0.5f) Ls[pre + __popcll(balS & below)] = (unsigned)(h * 4096);
        __syncthreads();
    }

    // ---- epilogue: features ----
    const float Lf   = (float)LSTEPS;
    const float mean = hysum / Lf;
    const float rms  = sqrtf(hysq / Lf + 1e-8f);
    float var = hysq / Lf - mean * mean;
    var = fmaxf(var, 1e-8f);
    float* ob = out + (size_t)b * (3 * NHID);
    ob[h]            = rms;
    ob[NHID + h]     = sqrtf(var);
    ob[2 * NHID + h] = hy;

    // ---- spike-count reduction (exact ints) ----
    unsigned int c = chrf;
    for (int off = 32; off > 0; off >>= 1) c += __shfl_down(c, off, 64);
    if (lane == 0) red[wv] = c;
    __syncthreads();
    if (h == 0) {
        unsigned int tot = 0;
        for (int i = 0; i < 16; ++i) tot += red[i];
        ws[b * 2] = tot;
    }
    __syncthreads();
    c = clif;
    for (int off = 32; off > 0; off >>= 1) c += __shfl_down(c, off, 64);
    if (lane == 0) red[wv] = c;
    __syncthreads();
    if (h == 0) {
        unsigned int tot = 0;
        for (int i = 0; i < 16; ++i) tot += red[i];
        ws[b * 2 + 1] = tot;
    }
}

__global__ void coesn_final(const unsigned int* __restrict__ ws,
                            float* __restrict__ out)
{
    if (threadIdx.x == 0 && blockIdx.x == 0) {
        unsigned long long hrf = 0, lif = 0;
        for (int b = 0; b < BATCH; ++b) {
            hrf += ws[b * 2];
            lif += ws[b * 2 + 1];
        }
        const float denom = (float)BATCH * (float)LSTEPS * (float)NHID;
        const float r_hrf = (float)hrf / denom;
        const float r_lif = (float)lif / denom;
        float* s = out + (size_t)BATCH * 3 * NHID;
        s[0] = r_hrf;
        s[1] = r_hrf;
        s[2] = r_lif;
    }
}

extern "C" void kernel_launch(void* const* d_in, const int* in_sizes, int n_in,
                              void* d_out, int out_size, void* d_ws, size_t ws_size,
                              hipStream_t stream) {
    const float* x       = (const float*)d_in[0];
    const float* x2h     = (const float*)d_in[1];
    const float* h2h     = (const float*)d_in[2];
    const float* bias    = (const float*)d_in[3];
    const float* lif2hrf = (const float*)d_in[4];
    const float* gamma_  = (const float*)d_in[5];
    const float* eps_    = (const float*)d_in[6];
    float* out = (float*)d_out;
    unsigned int* wsp = (unsigned int*)d_ws;

    coesn_sim<<<BATCH, NHID, 0, stream>>>(x, x2h, h2h, bias, lif2hrf, gamma_, eps_, out, wsp);
    coesn_final<<<1, 64, 0, stream>>>(wsp, out);
}